// Round 2
// baseline (600.256 us; speedup 1.0000x reference)
//
#include <hip/hip_runtime.h>
#include <hip/hip_bf16.h>
#include <stdint.h>
#include <math.h>

#define B_ 128
#define P_ 256
#define H_ 512
#define HEADS_ 8
#define HD_ 64
#define RANK_ 32
#define PH_ (P_*H_)        // 131072
#define TAU_ 0.3f
#define ALPHA_ 0.9f
#define EPS_ 1e-5f
#define BPP_ (B_*P_*P_)    // 8388608
#define N2_ (2*P_*RANK_)   // 16384
#define KCH_ 128           // split-K chunks for gemm0 (each 1024 k)

typedef __attribute__((ext_vector_type(4))) float floatx4;
typedef __attribute__((ext_vector_type(8))) short shortx8;

__device__ inline float wsum64(float v){
  #pragma unroll
  for (int m=32;m>0;m>>=1) v += __shfl_xor(v, m, 64);
  return v;
}
// DPP full-wave sum: result valid in lane 63 (VALU-rate, no LDS pipe)
__device__ inline float dpp_sum(float v){
  union{float f; int i;} u, t;
  u.f = v;
  t.i = __builtin_amdgcn_update_dpp(0, u.i, 0x111, 0xf, 0xf, true); u.f += t.f; // row_shr:1
  t.i = __builtin_amdgcn_update_dpp(0, u.i, 0x112, 0xf, 0xf, true); u.f += t.f; // row_shr:2
  t.i = __builtin_amdgcn_update_dpp(0, u.i, 0x114, 0xf, 0xf, true); u.f += t.f; // row_shr:4
  t.i = __builtin_amdgcn_update_dpp(0, u.i, 0x118, 0xf, 0xf, true); u.f += t.f; // row_shr:8
  t.i = __builtin_amdgcn_update_dpp(0, u.i, 0x142, 0xf, 0xf, true); u.f += t.f; // row_bcast:15
  t.i = __builtin_amdgcn_update_dpp(0, u.i, 0x143, 0xf, 0xf, true); u.f += t.f; // row_bcast:31
  return u.f;
}
__device__ inline unsigned short f2bf(float f){
  union{float f; uint32_t u;} a; a.f=f;
  uint32_t r = (a.u + 0x7fffu + ((a.u>>16)&1u))>>16;
  return (unsigned short)r;
}
__device__ inline shortx8 pack_bf16x8(floatx4 a, floatx4 b){
  shortx8 r;
  r[0]=(short)f2bf(a.x); r[1]=(short)f2bf(a.y); r[2]=(short)f2bf(a.z); r[3]=(short)f2bf(a.w);
  r[4]=(short)f2bf(b.x); r[5]=(short)f2bf(b.y); r[6]=(short)f2bf(b.z); r[7]=(short)f2bf(b.w);
  return r;
}
#define GLL16(gp, lp) __builtin_amdgcn_global_load_lds( \
    (const __attribute__((address_space(1))) unsigned int*)(gp), \
    (__attribute__((address_space(3))) unsigned int*)(lp), 16, 0, 0)

// ---------------- k1: head constants (block 0) + res = x@res_w^T+res_b (blocks 1..128) --------
__global__ void k_setup_res(const float* qw, const float* qb, const float* kw, const float* kb,
                        const float* vw, const float* vb,
                        const float* x, const float* rw, const float* rb,
                        float* HC, float* wvh, float* cvh, float* res){
  if(blockIdx.x == 0){
    int lane = threadIdx.x & 63, h = threadIdx.x >> 6;
    int j = h*64 + lane;
    float qwv=qw[j], qbv=qb[j], kwv=kw[j], kbv=kb[j], vwv=vw[j], vbv=vb[j];
    const float inv64 = 1.0f/64.0f;
    float mqw = wsum64(qwv)*inv64, mqb = wsum64(qbv)*inv64;
    float mkw = wsum64(kwv)*inv64, mkb = wsum64(kbv)*inv64;
    float mvw = wsum64(vwv)*inv64, mvb = wsum64(vbv)*inv64;
    float aq=qwv-mqw, cq=qbv-mqb, ak=kwv-mkw, ck=kbv-mkb, av=vwv-mvw, cv=vbv-mvb;
    float Aq=wsum64(aq*aq), Bq=wsum64(aq*cq), Cq=wsum64(cq*cq);
    float Ak=wsum64(ak*ak), Bk=wsum64(ak*ck), Ck=wsum64(ck*ck);
    float Av=wsum64(av*av), Bv=wsum64(av*cv), Cv=wsum64(cv*cv);
    float Dww=wsum64(aq*ak), Dwc=wsum64(aq*ck), Dcw=wsum64(cq*ak), Dcc=wsum64(cq*ck);
    wvh[j]=av; cvh[j]=cv;
    if(lane==0){
      float* o = HC + h*16;
      o[0]=Aq;o[1]=Bq;o[2]=Cq;o[3]=Ak;o[4]=Bk;o[5]=Ck;o[6]=Av;o[7]=Bv;o[8]=Cv;
      o[9]=Dww;o[10]=Dwc;o[11]=Dcw;o[12]=Dcc;
    }
  } else {
    __shared__ float xs[P_];
    int b = blockIdx.x - 1, n = threadIdx.x;
    if(n < P_) xs[n] = x[b*P_ + n];
    __syncthreads();
    float acc = rb[n];
    const float* w = rw + (size_t)n*P_;
    #pragma unroll 4
    for(int p=0;p<P_;p+=4){
      floatx4 wv = *(const floatx4*)(w+p);
      acc += xs[p]*wv.x + xs[p+1]*wv.y + xs[p+2]*wv.z + xs[p+3]*wv.w;
    }
    res[b*H_ + n] = acc;
  }
}

// ---------------- k2: attention (rank-1 logits), attn_mean + S1/S2, DPP reductions -----------
// Native v_exp/v_rsq/v_rcp (no OCML fixup sequences) — this kernel is pure VALU-bound.
__global__ __launch_bounds__(256) void k_attn(const float* x, const float* HCg,
        float* S1, float* S2, float* am_out){
  __shared__ float xs[P_];
  __shared__ float hcs[HEADS_*16];
  __shared__ float t1t[HEADS_*P_], t2t[HEADS_*P_], u1t[HEADS_*P_], u2t[HEADS_*P_];
  int tid = threadIdx.x;
  int b = blockIdx.x >> 3, qt = blockIdx.x & 7;
  int lane = tid & 63, wid = tid >> 6;
  if(tid < P_) xs[tid] = x[b*P_ + tid];
  if(tid < HEADS_*16) hcs[tid] = HCg[tid];
  __syncthreads();
  for(int idx = tid; idx < HEADS_*P_; idx += 256){
    int h = idx >> 8;
    const float* hc = hcs + h*16;
    float y = xs[idx & 255];
    float vk = (hc[3]*y*y + 2.0f*hc[4]*y + hc[5])*(1.0f/64.0f) + EPS_;
    float idk = __builtin_amdgcn_rsqf(vk);
    float vv = (hc[6]*y*y + 2.0f*hc[7]*y + hc[8])*(1.0f/64.0f) + EPS_;
    float idv = __builtin_amdgcn_rsqf(vv);
    t1t[idx] = y*idk; t2t[idx] = idk;
    u1t[idx] = y*idv; u2t[idx] = idv;
  }
  __syncthreads();
  int q0 = qt*32 + wid*8;   // wave owns 8 q rows; lane owns k = lane*4..lane*4+3
  float am[8][4];
  #pragma unroll
  for(int q=0;q<8;q++){ am[q][0]=0;am[q][1]=0;am[q][2]=0;am[q][3]=0; }
  const float C0 = 1.4426950408889634f/(16.0f*TAU_);  // log2(e)/(sqrt(P)*tau)
  for(int h=0;h<HEADS_;h++){
    const float* hc = hcs + h*16;
    float Aq=hc[0], Bq=hc[1], Cq=hc[2];
    float Dww=hc[9], Dwc=hc[10], Dcw=hc[11], Dcc=hc[12];
    floatx4 T1 = ((const floatx4*)t1t)[h*64 + lane];
    floatx4 T2 = ((const floatx4*)t2t)[h*64 + lane];
    floatx4 U1 = ((const floatx4*)u1t)[h*64 + lane];
    floatx4 U2 = ((const floatx4*)u2t)[h*64 + lane];
    #pragma unroll
    for(int q=0;q<8;q++){
      float xq = xs[q0+q];
      float vq = (Aq*xq*xq + 2.0f*Bq*xq + Cq)*(1.0f/64.0f) + EPS_;
      float idq = __builtin_amdgcn_rsqf(vq);
      float Ap = C0*idq*(xq*Dww + Dcw);
      float Bp = C0*idq*(xq*Dwc + Dcc);
      float e0 = __builtin_amdgcn_exp2f(Ap*T1.x + Bp*T2.x);
      float e1 = __builtin_amdgcn_exp2f(Ap*T1.y + Bp*T2.y);
      float e2 = __builtin_amdgcn_exp2f(Ap*T1.z + Bp*T2.z);
      float e3 = __builtin_amdgcn_exp2f(Ap*T1.w + Bp*T2.w);
      float s  = dpp_sum(e0+e1+e2+e3);
      float s1 = dpp_sum(e0*U1.x + e1*U1.y + e2*U1.z + e3*U1.w);
      float s2 = dpp_sum(e0*U2.x + e1*U2.y + e2*U2.z + e3*U2.w);
      float inv = __builtin_amdgcn_rcpf(__shfl(s, 63, 64));
      am[q][0] += e0*inv; am[q][1] += e1*inv; am[q][2] += e2*inv; am[q][3] += e3*inv;
      if(lane==63){
        S1[(b*HEADS_+h)*P_ + q0+q] = s1*inv;
        S2[(b*HEADS_+h)*P_ + q0+q] = s2*inv;
      }
    }
  }
  #pragma unroll
  for(int q=0;q<8;q++){
    floatx4 v;
    v.x=am[q][0]*0.125f; v.y=am[q][1]*0.125f; v.z=am[q][2]*0.125f; v.w=am[q][3]*0.125f;
    *(floatx4*)(am_out + (size_t)b*(P_*P_) + (size_t)(q0+q)*P_ + lane*4) = v;
  }
}

// ---------------- k3: assemble h, add residual, LayerNorm(affine), write z (bf16) ------------
__global__ __launch_bounds__(256) void k_hln(const float* S1, const float* S2, const float* res,
        const float* wvh, const float* cvh, const float* lng, const float* lnb,
        unsigned short* z){
  int tid=threadIdx.x, lane=tid&63, wid=tid>>6;
  int row = blockIdx.x*4 + wid;          // row = b*P + p
  int b = row >> 8, p = row & 255;
  float v[8]; float s=0, ss=0;
  #pragma unroll
  for(int i=0;i<8;i++){
    int j = i*64 + lane;
    float s1 = S1[(b*HEADS_+i)*P_ + p];
    float s2 = S2[(b*HEADS_+i)*P_ + p];
    float hv = s1*wvh[j] + s2*cvh[j] + ALPHA_*res[b*H_+j];
    v[i]=hv; s+=hv; ss+=hv*hv;
  }
  s = wsum64(s); ss = wsum64(ss);
  float m = s*(1.0f/512.0f);
  float var = ss*(1.0f/512.0f) - m*m;
  float inv = __builtin_amdgcn_rsqf(var + EPS_);
  size_t base = (size_t)b*PH_ + (size_t)p*H_;
  #pragma unroll
  for(int i=0;i<8;i++){
    int j = i*64 + lane;
    float o = (v[i]-m)*inv*lng[j] + lnb[j];
    z[base + j] = f2bf(o);
  }
}

// ---------------- k4: part[kch] = z(bf16) @ w0^T chunk, split-K MFMA, double-buffered --------
// 2-phase pipeline (loads for t+1 issued before MFMA of t; one __syncthreads per step).
// Same-XCD sibling swizzle: kch = bid&127, nt = bid>>7 keeps all 8 nt-siblings of a kch on
// one XCD (bid%8 invariant), so each 256 KB z-chunk is pulled into that XCD's L2 once
// instead of 8 XCDs each re-fetching it from L3.
__global__ __launch_bounds__(256) void k_gemm0(const unsigned short* zA, const float* w0, float* part){
  __shared__ unsigned short At[2][128*64];
  int tid = threadIdx.x, lane = tid&63, wid = tid>>6;
  int bid = blockIdx.x;
  int kch = bid & 127, nt = bid >> 7;
  int k0 = kch*1024;
  int ln15 = lane & 15, quad = lane >> 4;
  int r = nt*64 + wid*16 + ln15;          // output col = w0 row, one per lane
  const float* Brow = w0 + (size_t)r*PH_ + k0;
  floatx4 acc[8];
  #pragma unroll
  for(int m=0;m<8;m++) acc[m]=(floatx4)(0.0f);

  // prologue: stage k-step 0 into buf0, load B regs for step 0
  #pragma unroll
  for(int ps=0;ps<4;ps++){
    int idx = ps*256 + tid;
    int m = idx>>3, kgs = idx&7;
    int kg = kgs ^ (m&7);
    GLL16(zA + (size_t)m*PH_ + k0 + kg*8, &At[0][idx*8]);
  }
  floatx4 c0 = *(const floatx4*)(Brow + quad*8);
  floatx4 c1 = *(const floatx4*)(Brow + quad*8 + 4);
  floatx4 c2 = *(const floatx4*)(Brow + 32 + quad*8);
  floatx4 c3 = *(const floatx4*)(Brow + 32 + quad*8 + 4);
  __syncthreads();

  for(int t=0;t<16;t++){
    int cur = t&1;
    floatx4 n0,n1,n2,n3;
    if(t<15){
      int kk = (t+1)*64;
      #pragma unroll
      for(int ps=0;ps<4;ps++){
        int idx = ps*256 + tid;
        int m = idx>>3, kgs = idx&7;
        int kg = kgs ^ (m&7);
        GLL16(zA + (size_t)m*PH_ + k0 + kk + kg*8, &At[cur^1][idx*8]);
      }
      n0 = *(const floatx4*)(Brow + kk + quad*8);
      n1 = *(const floatx4*)(Brow + kk + quad*8 + 4);
      n2 = *(const floatx4*)(Brow + kk + 32 + quad*8);
      n3 = *(const floatx4*)(Brow + kk + 32 + quad*8 + 4);
    }
    shortx8 bfs[2];
    bfs[0] = pack_bf16x8(c0,c1);
    bfs[1] = pack_bf16x8(c2,c3);
    #pragma unroll
    for(int ksi=0;ksi<2;ksi++){
      int c = ksi*4 + quad;
      #pragma unroll
      for(int m=0;m<8;m++){
        int row = m*16 + ln15;
        shortx8 af = *(const shortx8*)(&At[cur][row*64 + ((c ^ (ln15&7))<<3)]);
        acc[m] = __builtin_amdgcn_mfma_f32_16x16x32_bf16(af, bfs[ksi], acc[m], 0,0,0);
      }
    }
    __syncthreads();   // drains next-step GLL+B loads (vmcnt 0) + gates buffer reuse
    if(t<15){ c0=n0; c1=n1; c2=n2; c3=n3; }
  }
  float* pbase = part + (size_t)kch*(128*512);
  int col = nt*64 + wid*16 + ln15;
  #pragma unroll
  for(int m=0;m<8;m++){
    #pragma unroll
    for(int rr=0;rr<4;rr++){
      int rowm = m*16 + quad*4 + rr;
      pbase[rowm*H_ + col] = acc[m][rr];
    }
  }
}

// ---------------- k5: reduce partials, relu(+bb0), z1 = relu(z0 @ w1^T + bb1) -> bf16 --------
__global__ __launch_bounds__(512) void k_mlp1(const float* part, const float* bb0,
        const float* w1, const float* bb1, unsigned short* z1){
  __shared__ float zs[H_];
  int b = blockIdx.x, tid = threadIdx.x;   // 512 threads, one column each
  float a = bb0[tid];
  const float* p = part + (size_t)b*H_ + tid;
  #pragma unroll 8
  for(int kc=0;kc<KCH_;kc++) a += p[(size_t)kc*(128*512)];
  zs[tid] = a>0.0f ? a : 0.0f;
  __syncthreads();
  float acc = bb1[tid];
  const float* w = w1 + (size_t)tid*H_;
  #pragma unroll 4
  for(int k=0;k<H_;k+=4){
    floatx4 wv = *(const floatx4*)(w+k);
    floatx4 zv = *(const floatx4*)(zs+k);   // wave-uniform LDS read: broadcast, conflict-free
    acc += zv.x*wv.x + zv.y*wv.y + zv.z*wv.z + zv.w*wv.w;
  }
  acc = acc>0.0f ? acc : 0.0f;
  z1[b*H_+tid] = f2bf(acc);
}

// ---------------- k6: z2 = z1(bf16) @ w2^T + bb2 ---------------------------------------------
// z1 is 128 KB -> L2-resident on every XCD. LDS staging + per-step barriers were pure overhead
// in this 1-block/CU kernel (no TLP to hide the barrier drain) — read A-fragments directly
// from global (L2-hot), no LDS, no __syncthreads (Common-mistake #7).
__global__ __launch_bounds__(256) void k_gemm2(const unsigned short* z1, const float* w2,
        const float* bb2, float* z2){
  int tid = threadIdx.x, lane = tid&63, wid = tid>>6;
  int nb = blockIdx.x*64;
  int ln15 = lane&15, quad = lane>>4;
  int r = nb + wid*16 + ln15;
  const float* Brow = w2 + (size_t)r*H_;
  const unsigned short* Arow = z1 + (size_t)ln15*H_;
  floatx4 acc[8];
  #pragma unroll
  for(int m=0;m<8;m++) acc[m]=(floatx4)(0.0f);
  #pragma unroll 2
  for(int kk=0;kk<512;kk+=64){
    floatx4 c0 = *(const floatx4*)(Brow + kk + quad*8);
    floatx4 c1 = *(const floatx4*)(Brow + kk + quad*8 + 4);
    floatx4 c2 = *(const floatx4*)(Brow + kk + 32 + quad*8);
    floatx4 c3 = *(const floatx4*)(Brow + kk + 32 + quad*8 + 4);
    shortx8 bfs[2];
    bfs[0] = pack_bf16x8(c0, c1);
    bfs[1] = pack_bf16x8(c2, c3);
    #pragma unroll
    for(int ksi=0;ksi<2;ksi++){
      int koff = kk + (ksi*4 + quad)*8;
      #pragma unroll
      for(int m=0;m<8;m++){
        shortx8 af = *(const shortx8*)(Arow + (size_t)m*16*H_ + koff);
        acc[m] = __builtin_amdgcn_mfma_f32_16x16x32_bf16(af, bfs[ksi], acc[m], 0,0,0);
      }
    }
  }
  int col = nb + wid*16 + ln15;
  float bias = bb2[col];
  #pragma unroll
  for(int m=0;m<8;m++){
    #pragma unroll
    for(int rr=0;rr<4;rr++){
      int rowm = m*16 + quad*4 + rr;
      z2[(size_t)rowm*N2_ + col] = acc[m][rr] + bias;
    }
  }
}

// ---------------- k7: coeffs = U @ V^T per batch ---------------------------------------------
__global__ __launch_bounds__(256) void k_coeffs(const float* z2, float* out){
  __shared__ float Ut[32*68];
  __shared__ float Vt[32*68];
  int tid=threadIdx.x;
  int b = blockIdx.x >> 4, it = (blockIdx.x>>2)&3, jt = blockIdx.x&3;
  int i0 = it*64, j0 = jt*64;
  const float* zb = z2 + (size_t)b*N2_;
  #pragma unroll
  for(int rep=0;rep<8;rep++){
    int lin = rep*256 + tid;
    int il = lin>>5, rr = lin&31;
    Ut[rr*68 + il] = zb[(i0+il)*RANK_ + rr];
    Vt[rr*68 + il] = zb[P_*RANK_ + (j0+il)*RANK_ + rr];
  }
  __syncthreads();
  int ti = tid>>4, tj = tid&15;
  floatx4 acc0=(floatx4)(0.0f), acc1=(floatx4)(0.0f), acc2=(floatx4)(0.0f), acc3=(floatx4)(0.0f);
  #pragma unroll 4
  for(int rr=0;rr<32;rr++){
    floatx4 u = *(const floatx4*)(&Ut[rr*68 + ti*4]);
    floatx4 vv = *(const floatx4*)(&Vt[rr*68 + tj*4]);
    acc0 += u.x*vv; acc1 += u.y*vv; acc2 += u.z*vv; acc3 += u.w*vv;
  }
  floatx4 accs[4] = {acc0, acc1, acc2, acc3};
  #pragma unroll
  for(int a=0;a<4;a++){
    int i = i0 + ti*4 + a;
    *(floatx4*)(out + (size_t)b*(P_*P_) + (size_t)i*P_ + j0 + tj*4) = accs[a];
  }
}

extern "C" void kernel_launch(void* const* d_in, const int* in_sizes, int n_in,
                              void* d_out, int out_size, void* d_ws, size_t ws_size,
                              hipStream_t stream) {
  const float* x   = (const float*)d_in[0];
  const float* qw  = (const float*)d_in[1];
  const float* qb  = (const float*)d_in[2];
  const float* kw  = (const float*)d_in[3];
  const float* kb  = (const float*)d_in[4];
  const float* vw  = (const float*)d_in[5];
  const float* vb  = (const float*)d_in[6];
  const float* rw  = (const float*)d_in[7];
  const float* rb  = (const float*)d_in[8];
  const float* lng = (const float*)d_in[9];
  const float* lnb = (const float*)d_in[10];
  const float* w0  = (const float*)d_in[11];
  const float* bb0 = (const float*)d_in[12];
  const float* w1  = (const float*)d_in[13];
  const float* bb1 = (const float*)d_in[14];
  const float* w2  = (const float*)d_in[15];
  const float* bb2 = (const float*)d_in[16];
  float* out = (float*)d_out;

  char* ws = (char*)d_ws;
  float* HC   = (float*)(ws + 0);                    // 512 B
  float* wvh  = (float*)(ws + 4096);                 // 2 KB
  float* cvh  = (float*)(ws + 8192);                 // 2 KB
  float* res  = (float*)(ws + 16384);                // 256 KB
  float* S1   = (float*)(ws + (1ull<<20));           // 1 MB
  float* S2   = (float*)(ws + (2ull<<20));           // 1 MB
  unsigned short* z  = (unsigned short*)(ws + (4ull<<20));    // 32 MB (bf16)
  float* part = (float*)(ws + (40ull<<20));          // 33.6 MB (128 x 128 x 512 f32)
  unsigned short* z1 = (unsigned short*)(ws + (110ull<<20));  // 128 KB
  float* z2   = (float*)(ws + (112ull<<20));         // 8 MB

  hipLaunchKernelGGL(k_setup_res, dim3(129), dim3(512), 0, stream,
                     qw,qb,kw,kb,vw,vb, x, rw, rb, HC, wvh, cvh, res);
  hipLaunchKernelGGL(k_attn,  dim3(1024), dim3(256), 0, stream, x, HC, S1, S2, out + BPP_);
  hipLaunchKernelGGL(k_hln,   dim3(8192), dim3(256), 0, stream, S1, S2, res, wvh, cvh, lng, lnb, z);
  hipLaunchKernelGGL(k_gemm0, dim3(KCH_*8), dim3(256), 0, stream, z, w0, part);
  hipLaunchKernelGGL(k_mlp1,  dim3(128), dim3(512), 0, stream, part, bb0, w1, bb1, z1);
  hipLaunchKernelGGL(k_gemm2, dim3(256), dim3(256), 0, stream, z1, w2, bb2, z2);
  hipLaunchKernelGGL(k_coeffs,dim3(2048), dim3(256), 0, stream, z2, out);
}

// Round 3
// 565.303 us; speedup vs baseline: 1.0618x; 1.0618x over previous
//
#include <hip/hip_runtime.h>
#include <hip/hip_bf16.h>
#include <stdint.h>
#include <math.h>

#define B_ 128
#define P_ 256
#define H_ 512
#define HEADS_ 8
#define HD_ 64
#define RANK_ 32
#define PH_ (P_*H_)        // 131072
#define TAU_ 0.3f
#define ALPHA_ 0.9f
#define EPS_ 1e-5f
#define BPP_ (B_*P_*P_)    // 8388608
#define N2_ (2*P_*RANK_)   // 16384
#define KCH_ 128           // split-K chunks for gemm0 (each 1024 k)

typedef __attribute__((ext_vector_type(4))) float floatx4;
typedef __attribute__((ext_vector_type(8))) short shortx8;

__device__ inline float wsum64(float v){
  #pragma unroll
  for (int m=32;m>0;m>>=1) v += __shfl_xor(v, m, 64);
  return v;
}
// DPP full-wave sum: result valid in lane 63 (VALU-rate, no LDS pipe)
__device__ inline float dpp_sum(float v){
  union{float f; int i;} u, t;
  u.f = v;
  t.i = __builtin_amdgcn_update_dpp(0, u.i, 0x111, 0xf, 0xf, true); u.f += t.f; // row_shr:1
  t.i = __builtin_amdgcn_update_dpp(0, u.i, 0x112, 0xf, 0xf, true); u.f += t.f; // row_shr:2
  t.i = __builtin_amdgcn_update_dpp(0, u.i, 0x114, 0xf, 0xf, true); u.f += t.f; // row_shr:4
  t.i = __builtin_amdgcn_update_dpp(0, u.i, 0x118, 0xf, 0xf, true); u.f += t.f; // row_shr:8
  t.i = __builtin_amdgcn_update_dpp(0, u.i, 0x142, 0xf, 0xf, true); u.f += t.f; // row_bcast:15
  t.i = __builtin_amdgcn_update_dpp(0, u.i, 0x143, 0xf, 0xf, true); u.f += t.f; // row_bcast:31
  return u.f;
}
__device__ inline unsigned short f2bf(float f){
  union{float f; uint32_t u;} a; a.f=f;
  uint32_t r = (a.u + 0x7fffu + ((a.u>>16)&1u))>>16;
  return (unsigned short)r;
}
__device__ inline shortx8 pack_bf16x8(floatx4 a, floatx4 b){
  shortx8 r;
  r[0]=(short)f2bf(a.x); r[1]=(short)f2bf(a.y); r[2]=(short)f2bf(a.z); r[3]=(short)f2bf(a.w);
  r[4]=(short)f2bf(b.x); r[5]=(short)f2bf(b.y); r[6]=(short)f2bf(b.z); r[7]=(short)f2bf(b.w);
  return r;
}
#define GLL16(gp, lp) __builtin_amdgcn_global_load_lds( \
    (const __attribute__((address_space(1))) unsigned int*)(gp), \
    (__attribute__((address_space(3))) unsigned int*)(lp), 16, 0, 0)

// ---------------- k1: head constants (block 0) + res = x@res_w^T+res_b (blocks 1..128) --------
__global__ void k_setup_res(const float* qw, const float* qb, const float* kw, const float* kb,
                        const float* vw, const float* vb,
                        const float* x, const float* rw, const float* rb,
                        float* HC, float* wvh, float* cvh, float* res){
  if(blockIdx.x == 0){
    int lane = threadIdx.x & 63, h = threadIdx.x >> 6;
    int j = h*64 + lane;
    float qwv=qw[j], qbv=qb[j], kwv=kw[j], kbv=kb[j], vwv=vw[j], vbv=vb[j];
    const float inv64 = 1.0f/64.0f;
    float mqw = wsum64(qwv)*inv64, mqb = wsum64(qbv)*inv64;
    float mkw = wsum64(kwv)*inv64, mkb = wsum64(kbv)*inv64;
    float mvw = wsum64(vwv)*inv64, mvb = wsum64(vbv)*inv64;
    float aq=qwv-mqw, cq=qbv-mqb, ak=kwv-mkw, ck=kbv-mkb, av=vwv-mvw, cv=vbv-mvb;
    float Aq=wsum64(aq*aq), Bq=wsum64(aq*cq), Cq=wsum64(cq*cq);
    float Ak=wsum64(ak*ak), Bk=wsum64(ak*ck), Ck=wsum64(ck*ck);
    float Av=wsum64(av*av), Bv=wsum64(av*cv), Cv=wsum64(cv*cv);
    float Dww=wsum64(aq*ak), Dwc=wsum64(aq*ck), Dcw=wsum64(cq*ak), Dcc=wsum64(cq*ck);
    wvh[j]=av; cvh[j]=cv;
    if(lane==0){
      float* o = HC + h*16;
      o[0]=Aq;o[1]=Bq;o[2]=Cq;o[3]=Ak;o[4]=Bk;o[5]=Ck;o[6]=Av;o[7]=Bv;o[8]=Cv;
      o[9]=Dww;o[10]=Dwc;o[11]=Dcw;o[12]=Dcc;
    }
  } else {
    __shared__ float xs[P_];
    int b = blockIdx.x - 1, n = threadIdx.x;
    if(n < P_) xs[n] = x[b*P_ + n];
    __syncthreads();
    float acc = rb[n];
    const float* w = rw + (size_t)n*P_;
    #pragma unroll 4
    for(int p=0;p<P_;p+=4){
      floatx4 wv = *(const floatx4*)(w+p);
      acc += xs[p]*wv.x + xs[p+1]*wv.y + xs[p+2]*wv.z + xs[p+3]*wv.w;
    }
    res[b*H_ + n] = acc;
  }
}

// ---------------- k2: attention + fused h-assembly/LayerNorm/z-write -------------------------
// Block (b,qt) computes attn_mean rows AND, since it already holds s1*inv/s2*inv for all 8
// heads x its 32 q-rows (lane 63), stashes them in LDS and finishes h = PV + alpha*res,
// LayerNorm(affine), z(bf16) in-block. Kills the separate k_hln dispatch, the S1/S2 global
// round-trip, and the per-4-row broadcast re-reads of res/wvh/cvh/ln_g/ln_b (~49 MB L2/L3).
// After the head loop, t1t/t2t space (dead) is overlaid with wvh/cvh/res/ln_g/ln_b.
__global__ __launch_bounds__(256) void k_attn(const float* x, const float* HCg,
        const float* res, const float* wvh, const float* cvh,
        const float* lng, const float* lnb,
        unsigned short* z, float* am_out){
  __shared__ float xs[P_];
  __shared__ float hcs[HEADS_*16];
  __shared__ float big[HEADS_*P_*4];     // t1t|t2t|u1t|u2t during head loop; overlay after
  __shared__ float s1s[HEADS_*32], s2s[HEADS_*32];
  float* t1t = big;
  float* t2t = big + HEADS_*P_;
  float* u1t = big + 2*HEADS_*P_;
  float* u2t = big + 3*HEADS_*P_;
  int tid = threadIdx.x;
  int b = blockIdx.x >> 3, qt = blockIdx.x & 7;
  int lane = tid & 63, wid = tid >> 6;
  if(tid < P_) xs[tid] = x[b*P_ + tid];
  if(tid < HEADS_*16) hcs[tid] = HCg[tid];
  __syncthreads();
  for(int idx = tid; idx < HEADS_*P_; idx += 256){
    int h = idx >> 8;
    const float* hc = hcs + h*16;
    float y = xs[idx & 255];
    float vk = (hc[3]*y*y + 2.0f*hc[4]*y + hc[5])*(1.0f/64.0f) + EPS_;
    float idk = __builtin_amdgcn_rsqf(vk);
    float vv = (hc[6]*y*y + 2.0f*hc[7]*y + hc[8])*(1.0f/64.0f) + EPS_;
    float idv = __builtin_amdgcn_rsqf(vv);
    t1t[idx] = y*idk; t2t[idx] = idk;
    u1t[idx] = y*idv; u2t[idx] = idv;
  }
  __syncthreads();
  int q0 = qt*32 + wid*8;   // wave owns 8 q rows; lane owns k = lane*4..lane*4+3
  float am[8][4];
  #pragma unroll
  for(int q=0;q<8;q++){ am[q][0]=0;am[q][1]=0;am[q][2]=0;am[q][3]=0; }
  const float C0 = 1.4426950408889634f/(16.0f*TAU_);  // log2(e)/(sqrt(P)*tau)
  for(int h=0;h<HEADS_;h++){
    const float* hc = hcs + h*16;
    float Aq=hc[0], Bq=hc[1], Cq=hc[2];
    float Dww=hc[9], Dwc=hc[10], Dcw=hc[11], Dcc=hc[12];
    floatx4 T1 = ((const floatx4*)t1t)[h*64 + lane];
    floatx4 T2 = ((const floatx4*)t2t)[h*64 + lane];
    floatx4 U1 = ((const floatx4*)u1t)[h*64 + lane];
    floatx4 U2 = ((const floatx4*)u2t)[h*64 + lane];
    #pragma unroll
    for(int q=0;q<8;q++){
      float xq = xs[q0+q];
      float vq = (Aq*xq*xq + 2.0f*Bq*xq + Cq)*(1.0f/64.0f) + EPS_;
      float idq = __builtin_amdgcn_rsqf(vq);
      float Ap = C0*idq*(xq*Dww + Dcw);
      float Bp = C0*idq*(xq*Dwc + Dcc);
      float e0 = __builtin_amdgcn_exp2f(Ap*T1.x + Bp*T2.x);
      float e1 = __builtin_amdgcn_exp2f(Ap*T1.y + Bp*T2.y);
      float e2 = __builtin_amdgcn_exp2f(Ap*T1.z + Bp*T2.z);
      float e3 = __builtin_amdgcn_exp2f(Ap*T1.w + Bp*T2.w);
      float s  = dpp_sum(e0+e1+e2+e3);
      float s1 = dpp_sum(e0*U1.x + e1*U1.y + e2*U1.z + e3*U1.w);
      float s2 = dpp_sum(e0*U2.x + e1*U2.y + e2*U2.z + e3*U2.w);
      float inv = __builtin_amdgcn_rcpf(__shfl(s, 63, 64));
      am[q][0] += e0*inv; am[q][1] += e1*inv; am[q][2] += e2*inv; am[q][3] += e3*inv;
      if(lane==63){
        int lp = wid*8 + q;          // local row in [0,32)
        s1s[h*32 + lp] = s1*inv;
        s2s[h*32 + lp] = s2*inv;
      }
    }
  }
  #pragma unroll
  for(int q=0;q<8;q++){
    floatx4 v;
    v.x=am[q][0]*0.125f; v.y=am[q][1]*0.125f; v.z=am[q][2]*0.125f; v.w=am[q][3]*0.125f;
    *(floatx4*)(am_out + (size_t)b*(P_*P_) + (size_t)(q0+q)*P_ + lane*4) = v;
  }
  // ---- fused h-assembly + LayerNorm + z write ----
  __syncthreads();                      // all waves done reading t1t..u2t, s1s/s2s complete
  float* wv = big;                      // overlay (t1t/t2t region, 2560 floats = 10 KB)
  float* cv = big + 512;
  float* rs = big + 1024;
  float* lg = big + 1536;
  float* lb = big + 2048;
  for(int i = tid; i < 512; i += 256){
    wv[i] = wvh[i];
    cv[i] = cvh[i];
    rs[i] = ALPHA_*res[b*H_ + i];
    lg[i] = lng[i];
    lb[i] = lnb[i];
  }
  __syncthreads();
  #pragma unroll
  for(int q=0;q<8;q++){
    int lp = wid*8 + q;                 // local row
    int p  = qt*32 + lp;                // global row in [0,256)
    float v[8]; float s=0, ss=0;
    #pragma unroll
    for(int i=0;i<8;i++){
      int j = i*64 + lane;              // j>>6 == i (head index)
      float hv = s1s[i*32+lp]*wv[j] + s2s[i*32+lp]*cv[j] + rs[j];
      v[i]=hv; s+=hv; ss+=hv*hv;
    }
    s = wsum64(s); ss = wsum64(ss);
    float m = s*(1.0f/512.0f);
    float var = ss*(1.0f/512.0f) - m*m;
    float inv = __builtin_amdgcn_rsqf(var + EPS_);
    size_t base = (size_t)b*PH_ + (size_t)p*H_;
    #pragma unroll
    for(int i=0;i<8;i++){
      int j = i*64 + lane;
      float o = (v[i]-m)*inv*lg[j] + lb[j];
      z[base + j] = f2bf(o);
    }
  }
}

// ---------------- k4: part[kch] = z(bf16) @ w0^T chunk, split-K MFMA, double-buffered --------
// 2-phase pipeline (loads for t+1 issued before MFMA of t; one __syncthreads per step).
// Same-XCD sibling swizzle: kch = bid&127, nt = bid>>7 keeps all 8 nt-siblings of a kch on
// one XCD (bid%8 invariant), so each 256 KB z-chunk is pulled into that XCD's L2 once.
__global__ __launch_bounds__(256) void k_gemm0(const unsigned short* zA, const float* w0, float* part){
  __shared__ unsigned short At[2][128*64];
  int tid = threadIdx.x, lane = tid&63, wid = tid>>6;
  int bid = blockIdx.x;
  int kch = bid & 127, nt = bid >> 7;
  int k0 = kch*1024;
  int ln15 = lane & 15, quad = lane >> 4;
  int r = nt*64 + wid*16 + ln15;          // output col = w0 row, one per lane
  const float* Brow = w0 + (size_t)r*PH_ + k0;
  floatx4 acc[8];
  #pragma unroll
  for(int m=0;m<8;m++) acc[m]=(floatx4)(0.0f);

  // prologue: stage k-step 0 into buf0, load B regs for step 0
  #pragma unroll
  for(int ps=0;ps<4;ps++){
    int idx = ps*256 + tid;
    int m = idx>>3, kgs = idx&7;
    int kg = kgs ^ (m&7);
    GLL16(zA + (size_t)m*PH_ + k0 + kg*8, &At[0][idx*8]);
  }
  floatx4 c0 = *(const floatx4*)(Brow + quad*8);
  floatx4 c1 = *(const floatx4*)(Brow + quad*8 + 4);
  floatx4 c2 = *(const floatx4*)(Brow + 32 + quad*8);
  floatx4 c3 = *(const floatx4*)(Brow + 32 + quad*8 + 4);
  __syncthreads();

  for(int t=0;t<16;t++){
    int cur = t&1;
    floatx4 n0,n1,n2,n3;
    if(t<15){
      int kk = (t+1)*64;
      #pragma unroll
      for(int ps=0;ps<4;ps++){
        int idx = ps*256 + tid;
        int m = idx>>3, kgs = idx&7;
        int kg = kgs ^ (m&7);
        GLL16(zA + (size_t)m*PH_ + k0 + kk + kg*8, &At[cur^1][idx*8]);
      }
      n0 = *(const floatx4*)(Brow + kk + quad*8);
      n1 = *(const floatx4*)(Brow + kk + quad*8 + 4);
      n2 = *(const floatx4*)(Brow + kk + 32 + quad*8);
      n3 = *(const floatx4*)(Brow + kk + 32 + quad*8 + 4);
    }
    shortx8 bfs[2];
    bfs[0] = pack_bf16x8(c0,c1);
    bfs[1] = pack_bf16x8(c2,c3);
    #pragma unroll
    for(int ksi=0;ksi<2;ksi++){
      int c = ksi*4 + quad;
      #pragma unroll
      for(int m=0;m<8;m++){
        int row = m*16 + ln15;
        shortx8 af = *(const shortx8*)(&At[cur][row*64 + ((c ^ (ln15&7))<<3)]);
        acc[m] = __builtin_amdgcn_mfma_f32_16x16x32_bf16(af, bfs[ksi], acc[m], 0,0,0);
      }
    }
    __syncthreads();   // drains next-step GLL+B loads (vmcnt 0) + gates buffer reuse
    if(t<15){ c0=n0; c1=n1; c2=n2; c3=n3; }
  }
  float* pbase = part + (size_t)kch*(128*512);
  int col = nt*64 + wid*16 + ln15;
  #pragma unroll
  for(int m=0;m<8;m++){
    #pragma unroll
    for(int rr=0;rr<4;rr++){
      int rowm = m*16 + quad*4 + rr;
      pbase[rowm*H_ + col] = acc[m][rr];
    }
  }
}

// ---------------- k5: reduce partials, relu(+bb0), z1 = relu(z0 @ w1^T + bb1) -> bf16 --------
__global__ __launch_bounds__(512) void k_mlp1(const float* part, const float* bb0,
        const float* w1, const float* bb1, unsigned short* z1){
  __shared__ float zs[H_];
  int b = blockIdx.x, tid = threadIdx.x;   // 512 threads, one column each
  float a = bb0[tid];
  const float* p = part + (size_t)b*H_ + tid;
  #pragma unroll 8
  for(int kc=0;kc<KCH_;kc++) a += p[(size_t)kc*(128*512)];
  zs[tid] = a>0.0f ? a : 0.0f;
  __syncthreads();
  float acc = bb1[tid];
  const float* w = w1 + (size_t)tid*H_;
  #pragma unroll 4
  for(int k=0;k<H_;k+=4){
    floatx4 wv = *(const floatx4*)(w+k);
    floatx4 zv = *(const floatx4*)(zs+k);   // wave-uniform LDS read: broadcast, conflict-free
    acc += zv.x*wv.x + zv.y*wv.y + zv.z*wv.z + zv.w*wv.w;
  }
  acc = acc>0.0f ? acc : 0.0f;
  z1[b*H_+tid] = f2bf(acc);
}

// ---------------- k6: z2 = z1(bf16) @ w2^T + bb2 (MFMA, swizzled LDS, double-buffered) -------
// (R1 form: LDS staging + 2-phase pipeline. At 1 block/CU there is no TLP; un-staged global
// A-reads left L2 latency exposed — measured regression in R2.)
__global__ __launch_bounds__(256) void k_gemm2(const unsigned short* z1, const float* w2,
        const float* bb2, float* z2){
  __shared__ unsigned short At[2][128*64];
  int tid = threadIdx.x, lane = tid&63, wid = tid>>6;
  int nb = blockIdx.x*64;
  int ln15 = lane&15, quad = lane>>4;
  int r = nb + wid*16 + ln15;
  const float* Brow = w2 + (size_t)r*H_;
  floatx4 acc[8];
  #pragma unroll
  for(int m=0;m<8;m++) acc[m]=(floatx4)(0.0f);

  // prologue: stage k-step 0, load B regs for step 0
  #pragma unroll
  for(int ps=0;ps<4;ps++){
    int idx = ps*256+tid;
    int m = idx>>3, kgs = idx&7;
    int kg = kgs ^ (m&7);
    GLL16(z1 + (size_t)m*H_ + kg*8, &At[0][idx*8]);
  }
  floatx4 c0 = *(const floatx4*)(Brow + quad*8);
  floatx4 c1 = *(const floatx4*)(Brow + quad*8 + 4);
  floatx4 c2 = *(const floatx4*)(Brow + 32 + quad*8);
  floatx4 c3 = *(const floatx4*)(Brow + 32 + quad*8 + 4);
  __syncthreads();

  for(int t=0;t<8;t++){
    int cur = t&1;
    floatx4 n0,n1,n2,n3;
    if(t<7){
      int kk = (t+1)*64;
      #pragma unroll
      for(int ps=0;ps<4;ps++){
        int idx = ps*256+tid;
        int m = idx>>3, kgs = idx&7;
        int kg = kgs ^ (m&7);
        GLL16(z1 + (size_t)m*H_ + kk + kg*8, &At[cur^1][idx*8]);
      }
      n0 = *(const floatx4*)(Brow + kk + quad*8);
      n1 = *(const floatx4*)(Brow + kk + quad*8 + 4);
      n2 = *(const floatx4*)(Brow + kk + 32 + quad*8);
      n3 = *(const floatx4*)(Brow + kk + 32 + quad*8 + 4);
    }
    shortx8 bfs[2];
    bfs[0] = pack_bf16x8(c0,c1);
    bfs[1] = pack_bf16x8(c2,c3);
    #pragma unroll
    for(int ksi=0;ksi<2;ksi++){
      int c = ksi*4 + quad;
      #pragma unroll
      for(int m=0;m<8;m++){
        int row = m*16 + ln15;
        shortx8 af = *(const shortx8*)(&At[cur][row*64 + ((c ^ (ln15&7))<<3)]);
        acc[m] = __builtin_amdgcn_mfma_f32_16x16x32_bf16(af, bfs[ksi], acc[m], 0,0,0);
      }
    }
    __syncthreads();
    if(t<7){ c0=n0; c1=n1; c2=n2; c3=n3; }
  }
  int col = nb + wid*16 + ln15;
  float bias = bb2[col];
  #pragma unroll
  for(int m=0;m<8;m++){
    #pragma unroll
    for(int rr=0;rr<4;rr++){
      int rowm = m*16 + quad*4 + rr;
      z2[(size_t)rowm*N2_ + col] = acc[m][rr] + bias;
    }
  }
}

// ---------------- k7: coeffs = U @ V^T per batch ---------------------------------------------
__global__ __launch_bounds__(256) void k_coeffs(const float* z2, float* out){
  __shared__ float Ut[32*68];
  __shared__ float Vt[32*68];
  int tid=threadIdx.x;
  int b = blockIdx.x >> 4, it = (blockIdx.x>>2)&3, jt = blockIdx.x&3;
  int i0 = it*64, j0 = jt*64;
  const float* zb = z2 + (size_t)b*N2_;
  #pragma unroll
  for(int rep=0;rep<8;rep++){
    int lin = rep*256 + tid;
    int il = lin>>5, rr = lin&31;
    Ut[rr*68 + il] = zb[(i0+il)*RANK_ + rr];
    Vt[rr*68 + il] = zb[P_*RANK_ + (j0+il)*RANK_ + rr];
  }
  __syncthreads();
  int ti = tid>>4, tj = tid&15;
  floatx4 acc0=(floatx4)(0.0f), acc1=(floatx4)(0.0f), acc2=(floatx4)(0.0f), acc3=(floatx4)(0.0f);
  #pragma unroll 4
  for(int rr=0;rr<32;rr++){
    floatx4 u = *(const floatx4*)(&Ut[rr*68 + ti*4]);
    floatx4 vv = *(const floatx4*)(&Vt[rr*68 + tj*4]);
    acc0 += u.x*vv; acc1 += u.y*vv; acc2 += u.z*vv; acc3 += u.w*vv;
  }
  floatx4 accs[4] = {acc0, acc1, acc2, acc3};
  #pragma unroll
  for(int a=0;a<4;a++){
    int i = i0 + ti*4 + a;
    *(floatx4*)(out + (size_t)b*(P_*P_) + (size_t)i*P_ + j0 + tj*4) = accs[a];
  }
}

extern "C" void kernel_launch(void* const* d_in, const int* in_sizes, int n_in,
                              void* d_out, int out_size, void* d_ws, size_t ws_size,
                              hipStream_t stream) {
  const float* x   = (const float*)d_in[0];
  const float* qw  = (const float*)d_in[1];
  const float* qb  = (const float*)d_in[2];
  const float* kw  = (const float*)d_in[3];
  const float* kb  = (const float*)d_in[4];
  const float* vw  = (const float*)d_in[5];
  const float* vb  = (const float*)d_in[6];
  const float* rw  = (const float*)d_in[7];
  const float* rb  = (const float*)d_in[8];
  const float* lng = (const float*)d_in[9];
  const float* lnb = (const float*)d_in[10];
  const float* w0  = (const float*)d_in[11];
  const float* bb0 = (const float*)d_in[12];
  const float* w1  = (const float*)d_in[13];
  const float* bb1 = (const float*)d_in[14];
  const float* w2  = (const float*)d_in[15];
  const float* bb2 = (const float*)d_in[16];
  float* out = (float*)d_out;

  char* ws = (char*)d_ws;
  float* HC   = (float*)(ws + 0);                    // 512 B
  float* wvh  = (float*)(ws + 4096);                 // 2 KB
  float* cvh  = (float*)(ws + 8192);                 // 2 KB
  float* res  = (float*)(ws + 16384);                // 256 KB
  unsigned short* z  = (unsigned short*)(ws + (4ull<<20));    // 32 MB (bf16)
  float* part = (float*)(ws + (40ull<<20));          // 33.6 MB (128 x 128 x 512 f32)
  unsigned short* z1 = (unsigned short*)(ws + (110ull<<20));  // 128 KB
  float* z2   = (float*)(ws + (112ull<<20));         // 8 MB

  hipLaunchKernelGGL(k_setup_res, dim3(129), dim3(512), 0, stream,
                     qw,qb,kw,kb,vw,vb, x, rw, rb, HC, wvh, cvh, res);
  hipLaunchKernelGGL(k_attn,  dim3(1024), dim3(256), 0, stream,
                     x, HC, res, wvh, cvh, lng, lnb, z, out + BPP_);
  hipLaunchKernelGGL(k_gemm0, dim3(KCH_*8), dim3(256), 0, stream, z, w0, part);
  hipLaunchKernelGGL(k_mlp1,  dim3(128), dim3(512), 0, stream, part, bb0, w1, bb1, z1);
  hipLaunchKernelGGL(k_gemm2, dim3(256), dim3(256), 0, stream, z1, w2, bb2, z2);
  hipLaunchKernelGGL(k_coeffs,dim3(2048), dim3(256), 0, stream, z2, out);
}